// Round 6
// baseline (197.240 us; speedup 1.0000x reference)
//
#include <hip/hip_runtime.h>

// x: [T=63, B=1, H=16, S=384, D=128] f32
// y: [T=63, B=1, H=16, D=128, S=384] f32
// out: [63, 1, 16, 384, 384] f32 = broadcast of per-head (mean_t x) @ (mean_t y)
#define T_DIM 63
#define H_DIM 16
#define S_DIM 384
#define D_DIM 128
#define SLICE_ELEMS (H_DIM * S_DIM * D_DIM)        // 786432 floats per t-slice
#define SLICE_F4    (SLICE_ELEMS / 4)              // 196608
#define OUT_TSTRIDE (H_DIM * S_DIM * S_DIM)        // 2359296 floats per t-slice of out
#define OUT_TSTR_F4 (OUT_TSTRIDE / 4)
#define RT_ROWS 8                                  // rows per tile (full 384-col width)
#define RT_PER_HEAD (S_DIM / RT_ROWS)              // 48 row-tiles per head

typedef float f32x4 __attribute__((ext_vector_type(4)));

// Kernel 1: temporal mean over T for both x and y. Pure read-bound (396 MB).
// (unchanged from R4/R5 — 1536 blocks, 9-deep load batches saturate MLP)
__global__ __launch_bounds__(256) void treduce_kernel(
    const float* __restrict__ x, const float* __restrict__ y,
    float* __restrict__ xb, float* __restrict__ yb) {
  int tid = blockIdx.x * 256 + threadIdx.x;      // 0 .. 2*SLICE_F4-1
  const f32x4* src;
  f32x4* dst;
  if (tid < SLICE_F4) {
    src = reinterpret_cast<const f32x4*>(x) + tid;
    dst = reinterpret_cast<f32x4*>(xb) + tid;
  } else {
    tid -= SLICE_F4;
    src = reinterpret_cast<const f32x4*>(y) + tid;
    dst = reinterpret_cast<f32x4*>(yb) + tid;
  }
  f32x4 acc = (f32x4)0.f;
#pragma unroll 9
  for (int t = 0; t < T_DIM; ++t) {
    f32x4 v = __builtin_nontemporal_load(src + (size_t)t * SLICE_F4);
    acc += v;
  }
  acc *= (1.0f / (float)T_DIM);
  *dst = acc;
}

// Kernel 2: fused GEMM + broadcast with full-row tiles.
// Block = one 8-row x 384-col slab of one head's w, computed once, then
// streamed to all 63 timesteps. grid = 16*48 = 768 blocks, block = 384 thr.
// Thread t: col4 = t%96 (consecutive lanes -> consecutive float4s -> every
// store instruction is 1KB contiguous per wave), rows {2g, 2g+1}, g = t/96.
// A slab (8x128 = 4KB) in LDS (broadcast reads); B read direct from global
// (lane-coalesced float4; 48x per-head re-read served by L2/L3).
__global__ __launch_bounds__(384) void gemm_bcast_rows(
    const float* __restrict__ xb, const float* __restrict__ yb,
    float* __restrict__ out) {
  __shared__ float As[RT_ROWS * D_DIM];   // 4 KB

  const int h    = blockIdx.x / RT_PER_HEAD;
  const int rt   = blockIdx.x % RT_PER_HEAD;
  const int row0 = rt * RT_ROWS;
  const int t    = threadIdx.x;

  const float* A = xb + (size_t)h * S_DIM * D_DIM + (size_t)row0 * D_DIM;
  const float* B = yb + (size_t)h * D_DIM * S_DIM;  // [128][384] row-major

  // Stage A slab: 256 float4.
  if (t < 256) {
    reinterpret_cast<f32x4*>(As)[t] = reinterpret_cast<const f32x4*>(A)[t];
  }
  __syncthreads();

  const int c4 = t % 96;          // float4-column 0..95
  const int g  = t / 96;          // 0..3
  const int r0 = g * 2;
  const int r1 = g * 2 + 1;

  const f32x4* B4 = reinterpret_cast<const f32x4*>(B) + c4;  // row stride 96 f32x4

  f32x4 acc0 = (f32x4)0.f;
  f32x4 acc1 = (f32x4)0.f;
#pragma unroll 8
  for (int k = 0; k < D_DIM; ++k) {
    f32x4 b  = B4[(size_t)k * 96];
    float a0 = As[r0 * D_DIM + k];   // wave-broadcast LDS read
    float a1 = As[r1 * D_DIM + k];
    acc0 += a0 * b;
    acc1 += a1 * b;
  }

  // Broadcast: 63 timesteps x 2 rows, 1KB-contiguous nt stores per wave.
  float* o = out + (size_t)h * S_DIM * S_DIM + (size_t)row0 * S_DIM;
  f32x4* o0 = reinterpret_cast<f32x4*>(o + (size_t)r0 * S_DIM) + c4;
  f32x4* o1 = reinterpret_cast<f32x4*>(o + (size_t)r1 * S_DIM) + c4;
#pragma unroll 9
  for (int tt = 0; tt < T_DIM; ++tt) {
    size_t off = (size_t)tt * OUT_TSTR_F4;
    __builtin_nontemporal_store(acc0, o0 + off);
    __builtin_nontemporal_store(acc1, o1 + off);
  }
}

extern "C" void kernel_launch(void* const* d_in, const int* in_sizes, int n_in,
                              void* d_out, int out_size, void* d_ws, size_t ws_size,
                              hipStream_t stream) {
  const float* x = (const float*)d_in[0];
  const float* y = (const float*)d_in[1];
  float* out = (float*)d_out;

  float* xb = (float*)d_ws;                 // 786432 floats
  float* yb = xb + SLICE_ELEMS;             // 786432 floats (6 MB total)

  treduce_kernel<<<dim3(2 * SLICE_F4 / 256), dim3(256), 0, stream>>>(x, y, xb, yb);
  gemm_bcast_rows<<<dim3(H_DIM * RT_PER_HEAD), dim3(384), 0, stream>>>(xb, yb, out);
}